// Round 1
// baseline (121.362 us; speedup 1.0000x reference)
//
#include <hip/hip_runtime.h>
#include <math.h>

typedef __attribute__((ext_vector_type(8))) short short8;
typedef __attribute__((ext_vector_type(4))) float float4v;

#define GH_ 256
#define GW_ 256
#define H_  128
#define W_  128
#define C_  64
#define OC_ 64
#define NB_ 4

static __device__ __forceinline__ unsigned short f2bf(float f) {
    union { float f; unsigned int u; } v; v.f = f;
    unsigned int u = v.u;
    unsigned int r = u + 0x7FFFu + ((u >> 16) & 1u);   // round-to-nearest-even
    return (unsigned short)(r >> 16);
}

// Fused prep:
//  z<4 : x[b][c][ih][iw] fp32 -> xbf[b][ih][iw][c] bf16 (c contiguous, B-side)
//  z==4: weight[c][o][kh][kw] fp32 -> wtb[t=kh*3+kw][o][c] bf16 (A-side)
__global__ __launch_bounds__(256) void prep(const float* __restrict__ x,
                                            const float* __restrict__ w,
                                            unsigned short* __restrict__ xbf,
                                            unsigned short* __restrict__ wtb) {
    int b = blockIdx.z;
    int tid = threadIdx.x;
    if (b == 4) {
        int flat = (blockIdx.y * 2 + blockIdx.x) * 256 + tid;
        if (flat < 9 * OC_ * C_) {
            int c = flat & 63, o = (flat >> 6) & 63, t = flat >> 12;
            int kh = t / 3, kw = t - kh * 3;
            wtb[flat] = f2bf(w[((c * OC_ + o) * 3 + kh) * 3 + kw]);
        }
        return;
    }
    int half = blockIdx.x, ih = blockIdx.y;
    __shared__ float xl[C_][65];
    int iw0 = half * 64;
    for (int i = tid; i < C_ * 64; i += 256) {
        int c = i >> 6, iw = i & 63;
        xl[c][iw] = x[(((b * C_ + c) * H_) + ih) * W_ + iw0 + iw];
    }
    __syncthreads();
    for (int i = tid; i < 64 * 32; i += 256) {
        int iw = i >> 5, cp = i & 31;
        unsigned int lo = f2bf(xl[2 * cp][iw]);
        unsigned int hi = f2bf(xl[2 * cp + 1][iw]);
        unsigned int* dst = (unsigned int*)(xbf +
            ((size_t)((b * H_ + ih) * W_ + iw0 + iw)) * C_);
        dst[cp] = lo | (hi << 16);
    }
}

// Block = (ypair, hp, b): 2 output rows (py=0,1), ALL 256 columns (both w-parities).
// 512 threads = 8 waves = (oh, py, xh). Each lane accumulates both parities for its
// pixel column and stores a contiguous float2 at w=2*xp -> full-line writebacks.
__global__ __launch_bounds__(512, 2) void pac_main(
    const unsigned short* __restrict__ xbf,
    const float* __restrict__ guide,
    const unsigned short* __restrict__ wtb,
    const float* __restrict__ bias,
    float* __restrict__ out)
{
    const int ypair = blockIdx.x;   // 0..63
    const int hp    = blockIdx.y;   // 0..1
    const int b     = blockIdx.z;   // 0..3
    const int tid = threadIdx.x;
    const int ntr = 1 + hp;         // taps along r
    const int nslot = 3 * ntr;      // wp0: ntr slots, wp1: 2*ntr slots

    __shared__ float klds[6][2][128];   // [slot][py][xp]

    // ---- gaussian affinity kern per (slot, py, xp) ----
    for (int i = tid; i < nslot * 256; i += 512) {
        int px = i & 255, slot = i >> 8;
        int py = px >> 7, xp = px & 127;
        int wp, r, q;
        if (slot < ntr) { wp = 0; r = slot; q = 0; }
        else { int s = slot - ntr; wp = 1; r = s >> 1; q = s & 1; }
        int yp = ypair * 2 + py;
        int h = 2 * yp + hp, w = 2 * xp + wp;
        int rr = yp + r, cl = xp + q;
        float kv = 0.f;
        if (rr < H_ && cl < W_) {
            int hh = rr * 2, ww = cl * 2;        // guide neighbor, always in-bounds
            const float* gb = guide + (size_t)b * 3 * GH_ * GW_;
            float s2 = 0.f;
            #pragma unroll
            for (int g = 0; g < 3; ++g) {
                float d = gb[(g * GH_ + hh) * GW_ + ww] - gb[(g * GH_ + h) * GW_ + w];
                s2 += d * d;
            }
            kv = __expf(-0.5f * s2);
        }
        klds[slot][py][xp] = kv;
    }
    __syncthreads();

    const int wave = tid >> 6, lane = tid & 63;
    const int l16 = lane & 15, qk = lane >> 4;
    const int oh  = wave & 1;              // o half: 0..1 -> obase
    const int py  = (wave >> 1) & 1;
    const int xh  = wave >> 2;             // x half: 0..1
    const int obase = oh * 32;
    const int xpb   = xh * 64;
    const int yp = ypair * 2 + py;
    const int h  = 2 * yp + hp;

    float acc0[2][4][4];   // wp=0 (w = 2xp)
    float acc1[2][4][4];   // wp=1 (w = 2xp+1)
    #pragma unroll
    for (int mf = 0; mf < 2; ++mf)
        #pragma unroll
        for (int nf = 0; nf < 4; ++nf)
            #pragma unroll
            for (int e = 0; e < 4; ++e) { acc0[mf][nf][e] = 0.f; acc1[mf][nf][e] = 0.f; }

    for (int r = 0; r <= hp; ++r) {
        int kh = hp ? 2 * r : 1;
        int row = yp + r; if (row > H_ - 1) row = H_ - 1;   // kern==0 kills clamped taps
        int s_c = r;                  // wp0, kw=1
        int s_l = ntr + 2 * r;        // wp1, q=0, kw=0
        int s_r = ntr + 2 * r + 1;    // wp1, q=1, kw=2

        // A fragments for kw=0,1,2 at this kh: A[m=o][k=c] = wtb[t][o][c]
        short8 af[3][2][2];
        #pragma unroll
        for (int kw3 = 0; kw3 < 3; ++kw3) {
            const short8* wbase = (const short8*)(wtb + (size_t)(kh * 3 + kw3) * OC_ * C_);
            #pragma unroll
            for (int mf = 0; mf < 2; ++mf) {
                int o = obase + mf * 16 + l16;
                af[kw3][mf][0] = wbase[(o * C_ + qk * 8) >> 3];
                af[kw3][mf][1] = wbase[(o * C_ + 32 + qk * 8) >> 3];
            }
        }

        #pragma unroll
        for (int nf = 0; nf < 4; ++nf) {
            int xp = xpb + nf * 16 + l16;
            int col0 = xp;
            int col1 = xp + 1; if (col1 > W_ - 1) col1 = W_ - 1;
            const short8* xb0 = (const short8*)(xbf +
                ((size_t)((b * H_ + row) * W_ + col0)) * C_);
            const short8* xb1 = (const short8*)(xbf +
                ((size_t)((b * H_ + row) * W_ + col1)) * C_);
            short8 b0a = xb0[qk],     b0b = xb0[4 + qk];
            short8 b1a = xb1[qk],     b1b = xb1[4 + qk];
            float kc = klds[s_c][py][xp];
            float kl = klds[s_l][py][xp];
            float kr = klds[s_r][py][xp];
            #pragma unroll
            for (int mf = 0; mf < 2; ++mf) {
                float4v d;
                d = (float4v){0.f, 0.f, 0.f, 0.f};
                d = __builtin_amdgcn_mfma_f32_16x16x32_bf16(af[1][mf][0], b0a, d, 0, 0, 0);
                d = __builtin_amdgcn_mfma_f32_16x16x32_bf16(af[1][mf][1], b0b, d, 0, 0, 0);
                #pragma unroll
                for (int e = 0; e < 4; ++e) acc0[mf][nf][e] += kc * d[e];
                d = (float4v){0.f, 0.f, 0.f, 0.f};
                d = __builtin_amdgcn_mfma_f32_16x16x32_bf16(af[0][mf][0], b0a, d, 0, 0, 0);
                d = __builtin_amdgcn_mfma_f32_16x16x32_bf16(af[0][mf][1], b0b, d, 0, 0, 0);
                #pragma unroll
                for (int e = 0; e < 4; ++e) acc1[mf][nf][e] += kl * d[e];
                d = (float4v){0.f, 0.f, 0.f, 0.f};
                d = __builtin_amdgcn_mfma_f32_16x16x32_bf16(af[2][mf][0], b1a, d, 0, 0, 0);
                d = __builtin_amdgcn_mfma_f32_16x16x32_bf16(af[2][mf][1], b1b, d, 0, 0, 0);
                #pragma unroll
                for (int e = 0; e < 4; ++e) acc1[mf][nf][e] += kr * d[e];
            }
        }
    }

    // ---- epilogue: bias + contiguous float2 stores ----
    float bv[2][4];
    #pragma unroll
    for (int mf = 0; mf < 2; ++mf)
        #pragma unroll
        for (int e = 0; e < 4; ++e)
            bv[mf][e] = bias[obase + mf * 16 + qk * 4 + e];

    #pragma unroll
    for (int mf = 0; mf < 2; ++mf)
        #pragma unroll
        for (int e = 0; e < 4; ++e) {
            int o = obase + mf * 16 + qk * 4 + e;
            float2* op = (float2*)(out + (((size_t)b * OC_ + o) * GH_ + h) * GW_);
            #pragma unroll
            for (int nf = 0; nf < 4; ++nf) {
                int xp = xpb + nf * 16 + l16;
                float2 v;
                v.x = acc0[mf][nf][e] + bv[mf][e];
                v.y = acc1[mf][nf][e] + bv[mf][e];
                op[xp] = v;
            }
        }
}

extern "C" void kernel_launch(void* const* d_in, const int* in_sizes, int n_in,
                              void* d_out, int out_size, void* d_ws, size_t ws_size,
                              hipStream_t stream) {
    const float* x     = (const float*)d_in[0];
    const float* guide = (const float*)d_in[1];
    const float* wgt   = (const float*)d_in[2];
    const float* bias  = (const float*)d_in[3];
    float* out = (float*)d_out;

    unsigned short* xbf = (unsigned short*)d_ws;                   // 8.39 MB
    unsigned short* wtb = xbf + (size_t)NB_ * H_ * W_ * C_;        // +72 KB

    prep<<<dim3(2, 128, 5), 256, 0, stream>>>(x, wgt, xbf, wtb);
    pac_main<<<dim3(64, 2, 4), 512, 0, stream>>>(xbf, guide, wtb, bias, out);
}

// Round 2
// 118.980 us; speedup vs baseline: 1.0200x; 1.0200x over previous
//
#include <hip/hip_runtime.h>
#include <math.h>

typedef __attribute__((ext_vector_type(8))) short short8;
typedef __attribute__((ext_vector_type(4))) float float4v;

#define GH_ 256
#define GW_ 256
#define H_  128
#define W_  128
#define C_  64
#define OC_ 64
#define NB_ 4

static __device__ __forceinline__ unsigned short f2bf(float f) {
    union { float f; unsigned int u; } v; v.f = f;
    unsigned int u = v.u;
    unsigned int r = u + 0x7FFFu + ((u >> 16) & 1u);   // round-to-nearest-even
    return (unsigned short)(r >> 16);
}

// Fused prep:
//  z<4 : x[b][c][ih][iw] fp32 -> xbf[b][ih][iw][c] bf16 (c contiguous, B-side)
//  z==4: weight[c][o][kh][kw] fp32 -> wtb[t=kh*3+kw][o][c] bf16 (A-side)
__global__ __launch_bounds__(256) void prep(const float* __restrict__ x,
                                            const float* __restrict__ w,
                                            unsigned short* __restrict__ xbf,
                                            unsigned short* __restrict__ wtb) {
    int b = blockIdx.z;
    int tid = threadIdx.x;
    if (b == 4) {
        int flat = (blockIdx.y * 2 + blockIdx.x) * 256 + tid;
        if (flat < 9 * OC_ * C_) {
            int c = flat & 63, o = (flat >> 6) & 63, t = flat >> 12;
            int kh = t / 3, kw = t - kh * 3;
            wtb[flat] = f2bf(w[((c * OC_ + o) * 3 + kh) * 3 + kw]);
        }
        return;
    }
    int half = blockIdx.x, ih = blockIdx.y;
    __shared__ float xl[C_][65];
    int iw0 = half * 64;
    // float4 reads: 64 iw = 16 float4 per channel row
    for (int i = tid; i < C_ * 16; i += 256) {
        int c = i >> 4, f4 = i & 15;
        const float4* src = (const float4*)(x +
            (((size_t)(b * C_ + c) * H_) + ih) * W_ + iw0 + f4 * 4);
        float4 rd = *src;
        xl[c][f4 * 4 + 0] = rd.x;
        xl[c][f4 * 4 + 1] = rd.y;
        xl[c][f4 * 4 + 2] = rd.z;
        xl[c][f4 * 4 + 3] = rd.w;
    }
    __syncthreads();
    for (int i = tid; i < 64 * 32; i += 256) {
        int iw = i >> 5, cp = i & 31;
        unsigned int lo = f2bf(xl[2 * cp][iw]);
        unsigned int hi = f2bf(xl[2 * cp + 1][iw]);
        unsigned int* dst = (unsigned int*)(xbf +
            ((size_t)((b * H_ + ih) * W_ + iw0 + iw)) * C_);
        dst[cp] = lo | (hi << 16);
    }
}

// Block = (ypair, b, hp): 2 output rows (py=0,1), ALL 256 columns (both w-parities).
// hp is blockIdx.z so that block id and id+256 differ in hp -> each CU hosts one
// light (hp=0, 1 tap-row) + one heavy (hp=1, 2 tap-rows) block: balanced.
// mf (o-half-of-half) is the OUTERMOST loop: acc live-set 32 VGPR, af 24 VGPR ->
// fits 128 VGPR -> __launch_bounds__(512,4) gives 2 blocks/CU = 4 waves/SIMD.
__global__ __launch_bounds__(512, 4) void pac_main(
    const unsigned short* __restrict__ xbf,
    const float* __restrict__ guide,
    const unsigned short* __restrict__ wtb,
    const float* __restrict__ bias,
    float* __restrict__ out)
{
    const int ypair = blockIdx.x;   // 0..63
    const int b     = blockIdx.y;   // 0..3
    const int hp    = blockIdx.z;   // 0..1
    const int tid = threadIdx.x;
    const int ntr = 1 + hp;         // taps along r
    const int nslot = 3 * ntr;      // wp0: ntr slots, wp1: 2*ntr slots

    __shared__ float klds[6][2][128];   // [slot][py][xp]

    // ---- gaussian affinity kern per (slot, py, xp) ----
    for (int i = tid; i < nslot * 256; i += 512) {
        int px = i & 255, slot = i >> 8;
        int py = px >> 7, xp = px & 127;
        int wp, r, q;
        if (slot < ntr) { wp = 0; r = slot; q = 0; }
        else { int s = slot - ntr; wp = 1; r = s >> 1; q = s & 1; }
        int yp = ypair * 2 + py;
        int h = 2 * yp + hp, w = 2 * xp + wp;
        int rr = yp + r, cl = xp + q;
        float kv = 0.f;
        if (rr < H_ && cl < W_) {
            int hh = rr * 2, ww = cl * 2;        // guide neighbor, always in-bounds
            const float* gb = guide + (size_t)b * 3 * GH_ * GW_;
            float s2 = 0.f;
            #pragma unroll
            for (int g = 0; g < 3; ++g) {
                float d = gb[(g * GH_ + hh) * GW_ + ww] - gb[(g * GH_ + h) * GW_ + w];
                s2 += d * d;
            }
            kv = __expf(-0.5f * s2);
        }
        klds[slot][py][xp] = kv;
    }
    __syncthreads();

    const int wave = tid >> 6, lane = tid & 63;
    const int l16 = lane & 15, qk = lane >> 4;
    const int oh  = wave & 1;              // o half: 0..1 -> obase
    const int py  = (wave >> 1) & 1;
    const int xh  = wave >> 2;             // x half: 0..1
    const int obase = oh * 32;
    const int xpb   = xh * 64;
    const int yp = ypair * 2 + py;
    const int h  = 2 * yp + hp;

    for (int mf = 0; mf < 2; ++mf) {
        float acc0[4][4];   // wp=0 (w = 2xp)   [nf][e]
        float acc1[4][4];   // wp=1 (w = 2xp+1)
        #pragma unroll
        for (int nf = 0; nf < 4; ++nf)
            #pragma unroll
            for (int e = 0; e < 4; ++e) { acc0[nf][e] = 0.f; acc1[nf][e] = 0.f; }

        const int o = obase + mf * 16 + l16;

        for (int r = 0; r <= hp; ++r) {
            int kh = hp ? 2 * r : 1;
            int row = yp + r; if (row > H_ - 1) row = H_ - 1;   // kern==0 kills clamped taps
            int s_c = r;                  // wp0, kw=1
            int s_l = ntr + 2 * r;        // wp1, q=0, kw=0
            int s_r = ntr + 2 * r + 1;    // wp1, q=1, kw=2

            // A fragments for kw=0,1,2 at this kh (this mf only): A[m=o][k=c]
            short8 af[3][2];
            #pragma unroll
            for (int kw3 = 0; kw3 < 3; ++kw3) {
                const short8* wbase = (const short8*)(wtb + (size_t)(kh * 3 + kw3) * OC_ * C_);
                af[kw3][0] = wbase[(o * C_ + qk * 8) >> 3];
                af[kw3][1] = wbase[(o * C_ + 32 + qk * 8) >> 3];
            }

            #pragma unroll
            for (int nf = 0; nf < 4; ++nf) {
                int xp = xpb + nf * 16 + l16;
                int col0 = xp;
                int col1 = xp + 1; if (col1 > W_ - 1) col1 = W_ - 1;
                const short8* xb0 = (const short8*)(xbf +
                    ((size_t)((b * H_ + row) * W_ + col0)) * C_);
                const short8* xb1 = (const short8*)(xbf +
                    ((size_t)((b * H_ + row) * W_ + col1)) * C_);
                short8 b0a = xb0[qk],     b0b = xb0[4 + qk];
                short8 b1a = xb1[qk],     b1b = xb1[4 + qk];
                float kc = klds[s_c][py][xp];
                float kl = klds[s_l][py][xp];
                float kr = klds[s_r][py][xp];
                float4v d;
                d = (float4v){0.f, 0.f, 0.f, 0.f};
                d = __builtin_amdgcn_mfma_f32_16x16x32_bf16(af[1][0], b0a, d, 0, 0, 0);
                d = __builtin_amdgcn_mfma_f32_16x16x32_bf16(af[1][1], b0b, d, 0, 0, 0);
                #pragma unroll
                for (int e = 0; e < 4; ++e) acc0[nf][e] += kc * d[e];
                d = (float4v){0.f, 0.f, 0.f, 0.f};
                d = __builtin_amdgcn_mfma_f32_16x16x32_bf16(af[0][0], b0a, d, 0, 0, 0);
                d = __builtin_amdgcn_mfma_f32_16x16x32_bf16(af[0][1], b0b, d, 0, 0, 0);
                #pragma unroll
                for (int e = 0; e < 4; ++e) acc1[nf][e] += kl * d[e];
                d = (float4v){0.f, 0.f, 0.f, 0.f};
                d = __builtin_amdgcn_mfma_f32_16x16x32_bf16(af[2][0], b1a, d, 0, 0, 0);
                d = __builtin_amdgcn_mfma_f32_16x16x32_bf16(af[2][1], b1b, d, 0, 0, 0);
                #pragma unroll
                for (int e = 0; e < 4; ++e) acc1[nf][e] += kr * d[e];
            }
        }

        // ---- epilogue for this mf: bias + contiguous float2 stores ----
        float bv[4];
        #pragma unroll
        for (int e = 0; e < 4; ++e)
            bv[e] = bias[obase + mf * 16 + qk * 4 + e];

        #pragma unroll
        for (int e = 0; e < 4; ++e) {
            int oo = obase + mf * 16 + qk * 4 + e;
            float2* op = (float2*)(out + (((size_t)b * OC_ + oo) * GH_ + h) * GW_);
            #pragma unroll
            for (int nf = 0; nf < 4; ++nf) {
                int xp = xpb + nf * 16 + l16;
                float2 v;
                v.x = acc0[nf][e] + bv[e];
                v.y = acc1[nf][e] + bv[e];
                op[xp] = v;
            }
        }
    }
}

extern "C" void kernel_launch(void* const* d_in, const int* in_sizes, int n_in,
                              void* d_out, int out_size, void* d_ws, size_t ws_size,
                              hipStream_t stream) {
    const float* x     = (const float*)d_in[0];
    const float* guide = (const float*)d_in[1];
    const float* wgt   = (const float*)d_in[2];
    const float* bias  = (const float*)d_in[3];
    float* out = (float*)d_out;

    unsigned short* xbf = (unsigned short*)d_ws;                   // 8.39 MB
    unsigned short* wtb = xbf + (size_t)NB_ * H_ * W_ * C_;        // +72 KB

    prep<<<dim3(2, 128, 5), 256, 0, stream>>>(x, wgt, xbf, wtb);
    pac_main<<<dim3(64, 4, 2), 512, 0, stream>>>(xbf, guide, wtb, bias, out);
}

// Round 4
// 106.151 us; speedup vs baseline: 1.1433x; 1.1209x over previous
//
#include <hip/hip_runtime.h>
#include <math.h>

typedef __attribute__((ext_vector_type(8))) short short8;
typedef __attribute__((ext_vector_type(4))) float float4v;

#define GH_ 256
#define GW_ 256
#define H_  128
#define W_  128
#define C_  64
#define OC_ 64
#define NB_ 4

static __device__ __forceinline__ unsigned short f2bf(float f) {
    union { float f; unsigned int u; } v; v.f = f;
    unsigned int u = v.u;
    unsigned int r = u + 0x7FFFu + ((u >> 16) & 1u);   // round-to-nearest-even
    return (unsigned short)(r >> 16);
}

// XOR swizzle within each 128B "col row" of xt: spreads the per-col 128B stride
// across 8 16B bank-group slots. Applied identically on write and read.
static __device__ __forceinline__ int swz(int byte) {
    return byte ^ (((byte >> 7) & 7) << 4);
}

// Tiny weight pack: 9 blocks, one tap each.
// weight[c][o][kh][kw] fp32 -> wtb[t=kh*3+kw][o][c] bf16 (A-side)
__global__ __launch_bounds__(512) void prep_w(const float* __restrict__ w,
                                              unsigned short* __restrict__ wtb) {
    const int t = blockIdx.x;
    const int kh = t / 3, kw = t - kh * 3;
    for (int i = threadIdx.x; i < OC_ * C_; i += 512) {
        int c = i & 63, o = (i >> 6) & 63;
        wtb[t * OC_ * C_ + i] = f2bf(w[((c * OC_ + o) * 3 + kh) * 3 + kw]);
    }
}

// Fused main: per-block LDS transpose of the 2+hp needed x-rows (no global
// barrier needed), then the R2 mf-outer MFMA loop reading B-fragments from LDS.
__global__ __launch_bounds__(512, 4) void pac_fused(
    const float* __restrict__ x,
    const float* __restrict__ guide,
    const unsigned short* __restrict__ wtb,
    const float* __restrict__ bias,
    float* __restrict__ out)
{
    __shared__ unsigned short xt[3 * 128 * 64];   // 49152 B, swizzled [lr][col][c] bf16
    __shared__ float xaux[64 * 33];               // 8448 B: xl (phase0) / klds (main)

    const int ypair = blockIdx.x;   // 0..63
    const int b     = blockIdx.y;   // 0..3
    const int hp    = blockIdx.z;   // 0..1
    const int tid   = threadIdx.x;
    const int R0    = ypair * 2;
    const int nrows = 2 + hp;       // rows of x this block consumes

    // ---------------- phase 0: in-block transpose x -> xt ----------------
    {
        float (*xl)[33] = (float (*)[33])xaux;
        const int c = tid >> 3, f4 = tid & 7;      // 64 ch x 8 float4 = 512 = blockDim
        for (int lr = 0; lr < nrows; ++lr) {
            int srow = R0 + lr; if (srow > H_ - 1) srow = H_ - 1;  // kern==0 kills clamp
            const float* xrow = x + (((size_t)(b * C_ + c) * H_) + srow) * W_;
            for (int qtr = 0; qtr < 4; ++qtr) {
                const int iw0 = qtr * 32;
                float4 rd = *(const float4*)(xrow + iw0 + f4 * 4);
                xl[c][f4 * 4 + 0] = rd.x;
                xl[c][f4 * 4 + 1] = rd.y;
                xl[c][f4 * 4 + 2] = rd.z;
                xl[c][f4 * 4 + 3] = rd.w;
                __syncthreads();
                #pragma unroll
                for (int j = 0; j < 2; ++j) {
                    int jj = tid + j * 512;                 // 1024 = 32 cols x 32 cp
                    int cl = jj >> 5, cp = jj & 31;
                    unsigned int lo = f2bf(xl[2 * cp][cl]);
                    unsigned int hi = f2bf(xl[2 * cp + 1][cl]);
                    int lin = ((lr * 128 + iw0 + cl) << 7) + cp * 4;
                    *(unsigned int*)((char*)xt + swz(lin)) = lo | (hi << 16);
                }
                __syncthreads();
            }
        }
    }

    // ---------------- gaussian affinity kern (klds overlays xl) ----------------
    const int ntr = 1 + hp;         // taps along r
    const int nslot = 3 * ntr;      // wp0: ntr slots, wp1: 2*ntr slots
    float (*klds)[2][128] = (float (*)[2][128])xaux;

    for (int i = tid; i < nslot * 256; i += 512) {
        int px = i & 255, slot = i >> 8;
        int py = px >> 7, xp = px & 127;
        int wp, r, q;
        if (slot < ntr) { wp = 0; r = slot; q = 0; }
        else { int s = slot - ntr; wp = 1; r = s >> 1; q = s & 1; }
        int yp = R0 + py;
        int h = 2 * yp + hp, w = 2 * xp + wp;
        int rr = yp + r, cl = xp + q;
        float kv = 0.f;
        if (rr < H_ && cl < W_) {
            int hh = rr * 2, ww = cl * 2;        // guide neighbor, always in-bounds
            const float* gb = guide + (size_t)b * 3 * GH_ * GW_;
            float s2 = 0.f;
            #pragma unroll
            for (int g = 0; g < 3; ++g) {
                float d = gb[(g * GH_ + hh) * GW_ + ww] - gb[(g * GH_ + h) * GW_ + w];
                s2 += d * d;
            }
            kv = __expf(-0.5f * s2);
        }
        klds[slot][py][xp] = kv;
    }
    __syncthreads();

    // ---------------- main MFMA loop ----------------
    const int wave = tid >> 6, lane = tid & 63;
    const int l16 = lane & 15, qk = lane >> 4;
    const int oh  = wave & 1;              // o half: 0..1 -> obase
    const int py  = (wave >> 1) & 1;
    const int xh  = wave >> 2;             // x half: 0..1
    const int obase = oh * 32;
    const int xpb   = xh * 64;
    const int yp = R0 + py;
    const int h  = 2 * yp + hp;

    for (int mf = 0; mf < 2; ++mf) {
        float acc0[4][4];   // wp=0 (w = 2xp)   [nf][e]
        float acc1[4][4];   // wp=1 (w = 2xp+1)
        #pragma unroll
        for (int nf = 0; nf < 4; ++nf)
            #pragma unroll
            for (int e = 0; e < 4; ++e) { acc0[nf][e] = 0.f; acc1[nf][e] = 0.f; }

        const int o = obase + mf * 16 + l16;

        for (int r = 0; r <= hp; ++r) {
            int kh = hp ? 2 * r : 1;
            int rowc = yp + r; if (rowc > H_ - 1) rowc = H_ - 1;
            int lr0 = rowc - R0;          // 0..2, local xt row
            int s_c = r;                  // wp0, kw=1
            int s_l = ntr + 2 * r;        // wp1, q=0, kw=0
            int s_r = ntr + 2 * r + 1;    // wp1, q=1, kw=2

            // A fragments for kw=0,1,2 at this kh (this mf only): A[m=o][k=c]
            short8 af[3][2];
            #pragma unroll
            for (int kw3 = 0; kw3 < 3; ++kw3) {
                const short8* wbase = (const short8*)(wtb + (size_t)(kh * 3 + kw3) * OC_ * C_);
                af[kw3][0] = wbase[(o * C_ + qk * 8) >> 3];
                af[kw3][1] = wbase[(o * C_ + 32 + qk * 8) >> 3];
            }

            #pragma unroll
            for (int nf = 0; nf < 4; ++nf) {
                int xp = xpb + nf * 16 + l16;
                int col1 = xp + 1; if (col1 > W_ - 1) col1 = W_ - 1;
                int base0 = ((lr0 * 128 + xp)   << 7) + qk * 16;
                int base1 = ((lr0 * 128 + col1) << 7) + qk * 16;
                short8 b0a = *(const short8*)((const char*)xt + swz(base0));
                short8 b0b = *(const short8*)((const char*)xt + swz(base0 + 64));
                short8 b1a = *(const short8*)((const char*)xt + swz(base1));
                short8 b1b = *(const short8*)((const char*)xt + swz(base1 + 64));
                float kc = klds[s_c][py][xp];
                float kl = klds[s_l][py][xp];
                float kr = klds[s_r][py][xp];
                float4v d;
                d = (float4v){0.f, 0.f, 0.f, 0.f};
                d = __builtin_amdgcn_mfma_f32_16x16x32_bf16(af[1][0], b0a, d, 0, 0, 0);
                d = __builtin_amdgcn_mfma_f32_16x16x32_bf16(af[1][1], b0b, d, 0, 0, 0);
                #pragma unroll
                for (int e = 0; e < 4; ++e) acc0[nf][e] += kc * d[e];
                d = (float4v){0.f, 0.f, 0.f, 0.f};
                d = __builtin_amdgcn_mfma_f32_16x16x32_bf16(af[0][0], b0a, d, 0, 0, 0);
                d = __builtin_amdgcn_mfma_f32_16x16x32_bf16(af[0][1], b0b, d, 0, 0, 0);
                #pragma unroll
                for (int e = 0; e < 4; ++e) acc1[nf][e] += kl * d[e];
                d = (float4v){0.f, 0.f, 0.f, 0.f};
                d = __builtin_amdgcn_mfma_f32_16x16x32_bf16(af[2][0], b1a, d, 0, 0, 0);
                d = __builtin_amdgcn_mfma_f32_16x16x32_bf16(af[2][1], b1b, d, 0, 0, 0);
                #pragma unroll
                for (int e = 0; e < 4; ++e) acc1[nf][e] += kr * d[e];
            }
        }

        // ---- epilogue for this mf: bias + contiguous float2 stores ----
        float bv[4];
        #pragma unroll
        for (int e = 0; e < 4; ++e)
            bv[e] = bias[obase + mf * 16 + qk * 4 + e];

        #pragma unroll
        for (int e = 0; e < 4; ++e) {
            int oo = obase + mf * 16 + qk * 4 + e;
            float2* op = (float2*)(out + (((size_t)b * OC_ + oo) * GH_ + h) * GW_);
            #pragma unroll
            for (int nf = 0; nf < 4; ++nf) {
                int xp = xpb + nf * 16 + l16;
                float2 v;
                v.x = acc0[nf][e] + bv[e];
                v.y = acc1[nf][e] + bv[e];
                op[xp] = v;
            }
        }
    }
}

extern "C" void kernel_launch(void* const* d_in, const int* in_sizes, int n_in,
                              void* d_out, int out_size, void* d_ws, size_t ws_size,
                              hipStream_t stream) {
    const float* x     = (const float*)d_in[0];
    const float* guide = (const float*)d_in[1];
    const float* wgt   = (const float*)d_in[2];
    const float* bias  = (const float*)d_in[3];
    float* out = (float*)d_out;

    unsigned short* wtb = (unsigned short*)d_ws;   // 72 KB only

    prep_w<<<dim3(9), 512, 0, stream>>>(wgt, wtb);
    pac_fused<<<dim3(64, 4, 2), 512, 0, stream>>>(x, guide, wtb, bias, out);
}

// Round 5
// 102.990 us; speedup vs baseline: 1.1784x; 1.0307x over previous
//
#include <hip/hip_runtime.h>
#include <math.h>

typedef __attribute__((ext_vector_type(8))) short short8;
typedef __attribute__((ext_vector_type(4))) float float4v;
typedef __attribute__((ext_vector_type(4))) unsigned int uint4v;

#define GH_ 256
#define GW_ 256
#define H_  128
#define W_  128
#define C_  64
#define OC_ 64
#define NB_ 4

static __device__ __forceinline__ unsigned short f2bf(float f) {
    union { float f; unsigned int u; } v; v.f = f;
    unsigned int u = v.u;
    unsigned int r = u + 0x7FFFu + ((u >> 16) & 1u);   // round-to-nearest-even
    return (unsigned short)(r >> 16);
}

// XOR swizzle within each 128B "col row" of xt: spreads the per-col 128B stride
// across 8 16B bank-group slots. Applied identically on write and read.
static __device__ __forceinline__ int swz(int byte) {
    return byte ^ (((byte >> 7) & 7) << 4);
}

// Tiny weight pack: 9 blocks, one tap each.
// weight[c][o][kh][kw] fp32 -> wtb[t=kh*3+kw][o][c] bf16 (A-side)
__global__ __launch_bounds__(512) void prep_w(const float* __restrict__ w,
                                              unsigned short* __restrict__ wtb) {
    const int t = blockIdx.x;
    const int kh = t / 3, kw = t - kh * 3;
    for (int i = threadIdx.x; i < OC_ * C_; i += 512) {
        int c = i & 63, o = (i >> 6) & 63;
        wtb[t * OC_ * C_ + i] = f2bf(w[((c * OC_ + o) * 3 + kh) * 3 + kw]);
    }
}

// Fused main, 1024 threads, 1 block/CU, both hp halves per block.
// Phase 0: direct coalesced transpose x rows R0..R0+2 -> swizzled LDS xt
//          (one ds_write_b128 per thread per row, ZERO staging barriers),
//          + merged klds (9 slots: 3 for hp=0, 6 for hp=1). One barrier total.
// Phase 1: 16 waves = (oh, py, xh, hp); mf-outer MFMA loop, B-frags from LDS.
__global__ __launch_bounds__(1024, 4) void pac_fused(
    const float* __restrict__ x,
    const float* __restrict__ guide,
    const unsigned short* __restrict__ wtb,
    const float* __restrict__ bias,
    float* __restrict__ out)
{
    __shared__ unsigned short xt[3 * 128 * 64];   // 49152 B, swizzled [lr][col][c] bf16
    __shared__ float klds[9][2][128];             // 9216 B

    const int ypair = blockIdx.x;   // 0..63
    const int b     = blockIdx.y;   // 0..3
    const int tid   = threadIdx.x;
    const int R0    = ypair * 2;

    // ---------------- phase 0a: direct transpose x -> xt ----------------
    {
        const int col = tid & 127;          // source iw / xt row
        const int cg  = tid >> 7;           // channel group 0..7 (8 ch each)
        #pragma unroll
        for (int lr = 0; lr < 3; ++lr) {
            int srow = R0 + lr; if (srow > H_ - 1) srow = H_ - 1;   // kern==0 kills clamp
            const float* xs = x + (((size_t)(b * C_ + cg * 8) * H_) + srow) * W_ + col;
            float v[8];
            #pragma unroll
            for (int j = 0; j < 8; ++j) v[j] = xs[(size_t)j * H_ * W_];
            unsigned int p0 = (unsigned int)f2bf(v[0]) | ((unsigned int)f2bf(v[1]) << 16);
            unsigned int p1 = (unsigned int)f2bf(v[2]) | ((unsigned int)f2bf(v[3]) << 16);
            unsigned int p2 = (unsigned int)f2bf(v[4]) | ((unsigned int)f2bf(v[5]) << 16);
            unsigned int p3 = (unsigned int)f2bf(v[6]) | ((unsigned int)f2bf(v[7]) << 16);
            int byte = ((lr * 128 + col) << 7) + cg * 16;
            *(uint4v*)((char*)xt + swz(byte)) = (uint4v){p0, p1, p2, p3};
        }
    }

    // ---------------- phase 0b: gaussian affinity kern, 9 slots ----------------
    for (int i = tid; i < 9 * 256; i += 1024) {
        int px = i & 255, gs = i >> 8;      // gs 0..8
        int py = px >> 7, xp = px & 127;
        int lhp = (gs < 3) ? 0 : 1;
        int ls  = (gs < 3) ? gs : gs - 3;
        int lntr = 1 + lhp;
        int wp, r, q;
        if (ls < lntr) { wp = 0; r = ls; q = 0; }
        else { int s = ls - lntr; wp = 1; r = s >> 1; q = s & 1; }
        int yp = R0 + py;
        int h = 2 * yp + lhp, w = 2 * xp + wp;
        int rr = yp + r, cl = xp + q;
        float kv = 0.f;
        if (rr < H_ && cl < W_) {
            int hh = rr * 2, ww = cl * 2;        // guide neighbor, always in-bounds
            const float* gb = guide + (size_t)b * 3 * GH_ * GW_;
            float s2 = 0.f;
            #pragma unroll
            for (int g = 0; g < 3; ++g) {
                float d = gb[(g * GH_ + hh) * GW_ + ww] - gb[(g * GH_ + h) * GW_ + w];
                s2 += d * d;
            }
            kv = __expf(-0.5f * s2);
        }
        klds[gs][py][xp] = kv;
    }
    __syncthreads();

    // ---------------- phase 1: main MFMA loop ----------------
    const int wave = tid >> 6, lane = tid & 63;
    const int l16 = lane & 15, qk = lane >> 4;
    const int oh  = wave & 1;              // o half: 0..1 -> obase
    const int py  = (wave >> 1) & 1;
    const int xh  = (wave >> 2) & 1;       // x half: 0..1
    const int hp  = wave >> 3;             // 0..1
    const int obase = oh * 32;
    const int xpb   = xh * 64;
    const int yp = R0 + py;
    const int h  = 2 * yp + hp;
    const int ntr = 1 + hp;
    const int kbase = hp ? 3 : 0;

    for (int mf = 0; mf < 2; ++mf) {
        float acc0[4][4];   // wp=0 (w = 2xp)   [nf][e]
        float acc1[4][4];   // wp=1 (w = 2xp+1)
        #pragma unroll
        for (int nf = 0; nf < 4; ++nf)
            #pragma unroll
            for (int e = 0; e < 4; ++e) { acc0[nf][e] = 0.f; acc1[nf][e] = 0.f; }

        const int o = obase + mf * 16 + l16;

        for (int r = 0; r <= hp; ++r) {
            int kh = hp ? 2 * r : 1;
            int rowc = yp + r; if (rowc > H_ - 1) rowc = H_ - 1;
            int lr0 = rowc - R0;          // 0..2, local xt row
            int s_c = kbase + r;                  // wp0, kw=1
            int s_l = kbase + ntr + 2 * r;        // wp1, q=0, kw=0
            int s_r = kbase + ntr + 2 * r + 1;    // wp1, q=1, kw=2

            // A fragments for kw=0,1,2 at this kh (this mf only): A[m=o][k=c]
            short8 af[3][2];
            #pragma unroll
            for (int kw3 = 0; kw3 < 3; ++kw3) {
                const short8* wbase = (const short8*)(wtb + (size_t)(kh * 3 + kw3) * OC_ * C_);
                af[kw3][0] = wbase[(o * C_ + qk * 8) >> 3];
                af[kw3][1] = wbase[(o * C_ + 32 + qk * 8) >> 3];
            }

            #pragma unroll
            for (int nf = 0; nf < 4; ++nf) {
                int xp = xpb + nf * 16 + l16;
                int col1 = xp + 1; if (col1 > W_ - 1) col1 = W_ - 1;
                int base0 = ((lr0 * 128 + xp)   << 7) + qk * 16;
                int base1 = ((lr0 * 128 + col1) << 7) + qk * 16;
                short8 b0a = *(const short8*)((const char*)xt + swz(base0));
                short8 b0b = *(const short8*)((const char*)xt + swz(base0 + 64));
                short8 b1a = *(const short8*)((const char*)xt + swz(base1));
                short8 b1b = *(const short8*)((const char*)xt + swz(base1 + 64));
                float kc = klds[s_c][py][xp];
                float kl = klds[s_l][py][xp];
                float kr = klds[s_r][py][xp];
                float4v d;
                d = (float4v){0.f, 0.f, 0.f, 0.f};
                d = __builtin_amdgcn_mfma_f32_16x16x32_bf16(af[1][0], b0a, d, 0, 0, 0);
                d = __builtin_amdgcn_mfma_f32_16x16x32_bf16(af[1][1], b0b, d, 0, 0, 0);
                #pragma unroll
                for (int e = 0; e < 4; ++e) acc0[nf][e] += kc * d[e];
                d = (float4v){0.f, 0.f, 0.f, 0.f};
                d = __builtin_amdgcn_mfma_f32_16x16x32_bf16(af[0][0], b0a, d, 0, 0, 0);
                d = __builtin_amdgcn_mfma_f32_16x16x32_bf16(af[0][1], b0b, d, 0, 0, 0);
                #pragma unroll
                for (int e = 0; e < 4; ++e) acc1[nf][e] += kl * d[e];
                d = (float4v){0.f, 0.f, 0.f, 0.f};
                d = __builtin_amdgcn_mfma_f32_16x16x32_bf16(af[2][0], b1a, d, 0, 0, 0);
                d = __builtin_amdgcn_mfma_f32_16x16x32_bf16(af[2][1], b1b, d, 0, 0, 0);
                #pragma unroll
                for (int e = 0; e < 4; ++e) acc1[nf][e] += kr * d[e];
            }
        }

        // ---- epilogue for this mf: bias + contiguous float2 stores ----
        float bv[4];
        #pragma unroll
        for (int e = 0; e < 4; ++e)
            bv[e] = bias[obase + mf * 16 + qk * 4 + e];

        #pragma unroll
        for (int e = 0; e < 4; ++e) {
            int oo = obase + mf * 16 + qk * 4 + e;
            float2* op = (float2*)(out + (((size_t)b * OC_ + oo) * GH_ + h) * GW_);
            #pragma unroll
            for (int nf = 0; nf < 4; ++nf) {
                int xp = xpb + nf * 16 + l16;
                float2 v;
                v.x = acc0[nf][e] + bv[e];
                v.y = acc1[nf][e] + bv[e];
                op[xp] = v;
            }
        }
    }
}

extern "C" void kernel_launch(void* const* d_in, const int* in_sizes, int n_in,
                              void* d_out, int out_size, void* d_ws, size_t ws_size,
                              hipStream_t stream) {
    const float* x     = (const float*)d_in[0];
    const float* guide = (const float*)d_in[1];
    const float* wgt   = (const float*)d_in[2];
    const float* bias  = (const float*)d_in[3];
    float* out = (float*)d_out;

    unsigned short* wtb = (unsigned short*)d_ws;   // 72 KB only

    prep_w<<<dim3(9), 512, 0, stream>>>(wgt, wtb);
    pac_fused<<<dim3(64, 4), 1024, 0, stream>>>(x, guide, wtb, bias, out);
}